// Round 4
// baseline (665.275 us; speedup 1.0000x reference)
//
#include <hip/hip_runtime.h>
#include <math.h>

#define NB 8
#define NA 720
#define ND 1024
#define NH 512
#define NW 512

#define DXF 0.00390625f
#define DTH_D (3.14159265358979323846 / 720.0)

using h2v = decltype(__builtin_amdgcn_cvt_pkrtz(0.0f, 0.0f));
static_assert(sizeof(h2v) == 4, "h2v must be 4 bytes");

// ---------------- Kernel 1: 11-tap conv along detector, left pad 10, *DTH ---------------
__global__ __launch_bounds__(256) void conv_kernel(const float* __restrict__ x,
                                                   const float* __restrict__ w,
                                                   float* __restrict__ y) {
    int row = blockIdx.x;                 // b*720 + a
    const float* xr = x + (size_t)row * ND;
    float* yr = y + (size_t)row * ND;

    __shared__ float s[16 + ND];
    __shared__ float wk[16];

    int tid = threadIdx.x;
    if (tid < 16) s[tid] = 0.0f;
    if (tid < 11) wk[tid] = w[tid] * (float)DTH_D;

    float4 v = ((const float4*)xr)[tid];
    *(float4*)&s[16 + tid * 4] = v;
    __syncthreads();

    int d0 = tid * 4;
    float o0 = 0.f, o1 = 0.f, o2 = 0.f, o3 = 0.f;
#pragma unroll
    for (int k = 0; k < 11; ++k) {
        float wv = wk[k];
        o0 = fmaf(wv, s[6 + d0 + k], o0);
        o1 = fmaf(wv, s[7 + d0 + k], o1);
        o2 = fmaf(wv, s[8 + d0 + k], o2);
        o3 = fmaf(wv, s[9 + d0 + k], o3);
    }
    *(float4*)&yr[d0] = make_float4(o0, o1, o2, o3);
}

// ---------------- Kernel 2: per-angle tables: cos, sin, C = 511.5 - 255.5*(cos+sin) ----
__global__ void table_kernel(float* __restrict__ ct, float* __restrict__ st,
                             float* __restrict__ cc) {
    int a = blockIdx.x * blockDim.x + threadIdx.x;
    if (a < NA) {
        float th = (float)((a + 0.5) * DTH_D);
        double thd = (double)th;
        double c = cos(thd), s = sin(thd);
        ct[a] = (float)c;
        st[a] = (float)s;
        cc[a] = (float)(511.5 - 255.5 * (c + s));
    }
}

// ---------------- Kernel 3: backprojection ---------------
// 256 blocks = 8 batches x (8 i-tiles x 4 j-tiles). Tile = 64 i x 128 j.
// 512 threads: wave wv (0..7) covers i = ibase + wv*8 + r (r=0..7); lane covers
// j-pair j = jbase + 2*lane + {0,1}.  u = i*cos + j*sin + C, detector-cell units.
// LDS sinogram rows stored as packed f16 (v, dv) entries + odd-pair shifted copy:
// one aligned ds_read_b64 serves both j-pixels; interp = fma on f16-unpacked vals.

__device__ __forceinline__ void async_ld16(const float* g, float* l) {
    __builtin_amdgcn_global_load_lds((const __attribute__((address_space(1))) void*)g,
                                     (__attribute__((address_space(3))) void*)l,
                                     16, 0, 0);
}

// vmcnt(0) only (lgkm/exp untouched), then barrier
#define WAIT_VM0_BARRIER() do { \
    asm volatile("" ::: "memory"); \
    __builtin_amdgcn_s_waitcnt(0x0F70); \
    __builtin_amdgcn_s_barrier(); \
    asm volatile("" ::: "memory"); \
} while (0)

// lgkmcnt(0) only (vm loads stay in flight!), then barrier
#define WAIT_LGKM_BARRIER() do { \
    asm volatile("" ::: "memory"); \
    __builtin_amdgcn_s_waitcnt(0xC70F); \
    __builtin_amdgcn_s_barrier(); \
    asm volatile("" ::: "memory"); \
} while (0)

static __device__ __forceinline__ float fractf_(float x) {
#if __has_builtin(__builtin_amdgcn_fractf)
    return __builtin_amdgcn_fractf(x);
#else
    return x - floorf(x);
#endif
}

static __device__ __forceinline__ unsigned pk_f16(float v, float d) {
    h2v h = __builtin_amdgcn_cvt_pkrtz(v, d);
    return __builtin_bit_cast(unsigned, h);
}

#define NCHUNK 360   // 2 angles per chunk

__global__ __launch_bounds__(512) void bp_kernel(const float* __restrict__ sino,
                                                 const float* __restrict__ ct,
                                                 const float* __restrict__ st,
                                                 const float* __restrict__ cc,
                                                 float* __restrict__ out) {
    int bid = blockIdx.x;
    int b = bid >> 5;                  // 0..7
    int tile = bid & 31;
    int ibase = (tile >> 2) * 64;      // 8 i-tiles
    int jbase = (tile & 3) * 128;      // 4 j-tiles

    int tid = threadIdx.x;
    int lane = tid & 63;
    int wv = tid >> 6;                 // 0..7

    int j0 = jbase + 2 * lane;
    float fj = (float)j0;
    float fi0 = (float)(ibase + wv * 8);

    // cop[buf][angle][2048 dwords]: [0..1023] entries e_d = pk(v_d, v_{d+1}-v_d)
    //                               [1024..2047] odd pairs (e_{2m+1}, e_{2m+2})
    __shared__ unsigned cop[2][2][2048];            // 32 KB
    __shared__ float raw[2][2][1040];               // 16.6 KB (16-dword zero pad)

    const float* srow = sino + (size_t)b * (NA * ND);

    int ar = wv >> 2;        // which of the 2 angle rows this wave stages/repacks
    int q = wv & 3;          // quarter of the row
    int d0 = q * 256 + 4 * lane;   // dword span this lane repacks

    // zero the pads once (raw buffers' staging never touches [1024..1039])
    if (tid < 64) {
        int pb = (tid >> 5) & 1, pr = (tid >> 4) & 1, pk_ = tid & 15;
        raw[pb][pr][1024 + pk_] = 0.0f;
    }

    float acc0[8], acc1[8];
#pragma unroll
    for (int r = 0; r < 8; ++r) { acc0[r] = 0.0f; acc1[r] = 0.0f; }

    // ---- prologue: load chunk 0, repack it, start loads for chunk 1 ----
    async_ld16(srow + (size_t)(0 * 2 + ar) * ND + q * 256 + lane * 4,
               &raw[0][ar][q * 256 + lane * 4]);
    __syncthreads();   // full drain once: pads + chunk0 loads

    {
        const float* rw = &raw[0][ar][0];
        float4 ya = *(const float4*)&rw[d0];
        float4 yb = *(const float4*)&rw[d0 + 4];
        unsigned e0 = pk_f16(ya.x, ya.y - ya.x);
        unsigned e1 = pk_f16(ya.y, ya.z - ya.y);
        unsigned e2 = pk_f16(ya.z, ya.w - ya.z);
        unsigned e3 = pk_f16(ya.w, yb.x - ya.w);
        unsigned e4 = pk_f16(yb.x, yb.y - yb.x);
        *(uint4*)&cop[0][ar][d0] = make_uint4(e0, e1, e2, e3);
        *(uint4*)&cop[0][ar][1024 + d0] = make_uint4(e1, e2, e3, e4);
    }
    async_ld16(srow + (size_t)(1 * 2 + ar) * ND + q * 256 + lane * 4,
               &raw[1][ar][q * 256 + lane * 4]);
    WAIT_LGKM_BARRIER();

    for (int c = 0; c < NCHUNK; ++c) {
        int cur = c & 1;
        // ---- compute: 2 angles from cop[cur] ----
#pragma unroll
        for (int a = 0; a < 2; ++a) {
            int ang = c * 2 + a;
            float ca = ct[ang];
            float sa = st[ang];
            float Cc = cc[ang];
            const unsigned char* cb = (const unsigned char*)&cop[cur][a][0];
            float u = fmaf(fi0, ca, fmaf(fj, sa, Cc));
#pragma unroll
            for (int r = 0; r < 8; ++r) {
                int iu = (int)u;
                float g = fractf_(u);
                int off = ((iu >> 1) << 3) + ((iu & 1) << 12);
                uint2 w = *(const uint2*)(cb + off);
                h2v h0 = __builtin_bit_cast(h2v, w.x);
                // px0 (j0): f = g, entry iu
                acc0[r] = fmaf(g, (float)h0.y, acc0[r]);
                acc0[r] += (float)h0.x;
                // px1 (j0+1): t = g + sin, entry iu or iu+1
                float t = g + sa;
                unsigned ws = (t >= 1.0f) ? w.y : w.x;
                h2v hs = __builtin_bit_cast(h2v, ws);
                float f1 = fractf_(t);
                acc1[r] = fmaf(f1, (float)hs.y, acc1[r]);
                acc1[r] += (float)hs.x;
                u += ca;
            }
        }
        if (c == NCHUNK - 1) break;

        WAIT_VM0_BARRIER();            // raw[(c+1)&1] fully loaded (all waves)

        // ---- repack chunk c+1: raw -> cop ----
        {
            const float* rw = &raw[cur ^ 1][ar][0];
            float4 ya = *(const float4*)&rw[d0];
            float4 yb = *(const float4*)&rw[d0 + 4];
            unsigned e0 = pk_f16(ya.x, ya.y - ya.x);
            unsigned e1 = pk_f16(ya.y, ya.z - ya.y);
            unsigned e2 = pk_f16(ya.z, ya.w - ya.z);
            unsigned e3 = pk_f16(ya.w, yb.x - ya.w);
            unsigned e4 = pk_f16(yb.x, yb.y - yb.x);
            *(uint4*)&cop[cur ^ 1][ar][d0] = make_uint4(e0, e1, e2, e3);
            *(uint4*)&cop[cur ^ 1][ar][1024 + d0] = make_uint4(e1, e2, e3, e4);
        }
        // ---- start loads for chunk c+2 into raw[c&1] ----
        if (c + 2 < NCHUNK) {
            async_ld16(srow + (size_t)((c + 2) * 2 + ar) * ND + q * 256 + lane * 4,
                       &raw[cur][ar][q * 256 + lane * 4]);
        }
        WAIT_LGKM_BARRIER();           // cop[(c+1)&1] visible; vm loads stay in flight
    }

    float* orow = out + (size_t)b * (NH * NW);
#pragma unroll
    for (int r = 0; r < 8; ++r) {
        int i = ibase + wv * 8 + r;
        *(float2*)&orow[(size_t)i * NW + j0] = make_float2(acc0[r], acc1[r]);
    }
}

extern "C" void kernel_launch(void* const* d_in, const int* in_sizes, int n_in,
                              void* d_out, int out_size, void* d_ws, size_t ws_size,
                              hipStream_t stream) {
    const float* x = (const float*)d_in[0];      // [8,1,720,1024] f32
    const float* w = (const float*)d_in[1];      // [1,1,1,11] f32
    float* out = (float*)d_out;                  // [8,1,512,512] f32
    float* ws = (float*)d_ws;

    float* sino = ws;                            // 8*720*1024 floats
    float* ct = ws + (size_t)NB * NA * ND;
    float* st = ct + NA;
    float* cc = st + NA;

    conv_kernel<<<dim3(NB * NA), dim3(256), 0, stream>>>(x, w, sino);
    table_kernel<<<dim3(3), dim3(256), 0, stream>>>(ct, st, cc);
    bp_kernel<<<dim3(256), dim3(512), 0, stream>>>(sino, ct, st, cc, out);
}